// Round 1
// baseline (295.069 us; speedup 1.0000x reference)
//
#include <hip/hip_runtime.h>
#include <stdint.h>

typedef short short8 __attribute__((ext_vector_type(8)));
typedef float f32x4 __attribute__((ext_vector_type(4)));
typedef unsigned short u16;
typedef unsigned int u32;

struct alignas(8) U16x4 { u16 x, y, z, w; };

__device__ __forceinline__ u16 f2bf(float f) {
  u32 u = __float_as_uint(f);
  u += 0x7fffu + ((u >> 16) & 1u);
  return (u16)(u >> 16);
}

__device__ __forceinline__ void gld_lds16(const u16* g, u16* l) {
  __builtin_amdgcn_global_load_lds((const __attribute__((address_space(1))) u32*)g,
                                   (__attribute__((address_space(3))) u32*)l,
                                   16, 0, 0);
}

__device__ __forceinline__ void mfma16x16x32(f32x4& c, short8 a, short8 b) {
  asm("v_mfma_f32_16x16x32_bf16 %0, %1, %2, %0" : "+v"(c) : "v"(a), "v"(b));
}

// ---------------------------------------------------------------------------
// Generic batched C = A * B^T  (A: [M,K] row-major, Bt: [N,K] row-major)
// EPI: 0 = none (bf16 out), 1 = +v1[row] (bf16), 2 = +v1[col] (bf16),
//      3 = *1/512 (bf16), 4 = acc*v1[row] + v2[row] + xres (f32 out)
// All of M, N divisible by 128; K divisible by 64.
// ---------------------------------------------------------------------------
template<int EPI>
__global__ void gemm_abt(const u16* __restrict__ A, int64_t Abs,
                         const u16* __restrict__ Bt, int64_t Bbs,
                         void* __restrict__ Cptr, int64_t Cbs,
                         int M, int N, int K,
                         const float* __restrict__ v1,
                         const float* __restrict__ v2,
                         const float* __restrict__ xres) {
  constexpr int BM = 128, BN = 128, BK = 64;
  __shared__ u16 As[BM * BK];
  __shared__ u16 Bs[BN * BK];

  const int b = blockIdx.z;
  const u16* Ab = A + (int64_t)b * Abs;
  const u16* Bb = Bt + (int64_t)b * Bbs;
  const int brow = blockIdx.y * BM, bcol = blockIdx.x * BN;
  const int tid = threadIdx.x, lane = tid & 63, w = tid >> 6;
  const int wr = w >> 1, wc = w & 1;

  f32x4 acc[4][4] = {};

  // staging: thread t loads 16B at row (t>>3)+i*32, col-offset (t&7)*8 elems
  const int sr = tid >> 3;
  const int sc = (tid & 7) * 8;
  u16* lA = &As[sr * BK + sc];
  u16* lB = &Bs[sr * BK + sc];
  const u16* gA = Ab + (int64_t)(brow + sr) * K + sc;
  const u16* gB = Bb + (int64_t)(bcol + sr) * K + sc;

  const int la16 = lane & 15;
  const int kg = (lane >> 4) * 8;

  for (int k0 = 0; k0 < K; k0 += BK) {
#pragma unroll
    for (int i = 0; i < 4; ++i) gld_lds16(gA + (int64_t)i * 32 * K + k0, lA + i * 32 * BK);
#pragma unroll
    for (int i = 0; i < 4; ++i) gld_lds16(gB + (int64_t)i * 32 * K + k0, lB + i * 32 * BK);
    __syncthreads();
#pragma unroll
    for (int kk = 0; kk < 2; ++kk) {
      short8 af[4], bf[4];
#pragma unroll
      for (int m = 0; m < 4; ++m)
        af[m] = *(const short8*)&As[(wr * 64 + m * 16 + la16) * BK + kk * 32 + kg];
#pragma unroll
      for (int n = 0; n < 4; ++n)
        bf[n] = *(const short8*)&Bs[(wc * 64 + n * 16 + la16) * BK + kk * 32 + kg];
#pragma unroll
      for (int m = 0; m < 4; ++m)
#pragma unroll
        for (int n = 0; n < 4; ++n)
          mfma16x16x32(acc[m][n], af[m], bf[n]);
    }
    __syncthreads();
  }
  asm volatile("s_nop 7\n\ts_nop 7");  // MFMA->VALU read hazard guard (asm mfma)

  // D frag (m,n): row = brow + wr*64 + m*16 + (lane>>4)*4 + r, col = bcol + wc*64 + n*16 + (lane&15)
  const int r0 = brow + wr * 64 + (lane >> 4) * 4;
  const int c0 = bcol + wc * 64 + la16;

  if (EPI == 4) {
    float* Cb = (float*)Cptr + (int64_t)b * Cbs;
    const float* xb = xres + (int64_t)b * Cbs;
#pragma unroll
    for (int m = 0; m < 4; ++m) {
#pragma unroll
      for (int r = 0; r < 4; ++r) {
        const int row = r0 + m * 16 + r;
        const float scl = v1[row], shf = v2[row];
#pragma unroll
        for (int n = 0; n < 4; ++n) {
          const int col = c0 + n * 16;
          Cb[(int64_t)row * N + col] = acc[m][n][r] * scl + shf + xb[(int64_t)row * N + col];
        }
      }
    }
  } else {
    u16* Cb = (u16*)Cptr + (int64_t)b * Cbs;
#pragma unroll
    for (int m = 0; m < 4; ++m)
#pragma unroll
      for (int n = 0; n < 4; ++n)
#pragma unroll
        for (int r = 0; r < 4; ++r) {
          const int row = r0 + m * 16 + r, col = c0 + n * 16;
          float v = acc[m][n][r];
          if (EPI == 1) v += v1[row];
          if (EPI == 2) v += v1[col];
          if (EPI == 3) v *= (1.0f / 512.0f);
          Cb[(int64_t)row * N + col] = f2bf(v);
        }
  }
}

// fp32 [C,N] -> bf16 [N,C] per batch (32x32 tiles)
__global__ void transpose_cvt(const float* __restrict__ in, u16* __restrict__ out,
                              int C, int N) {
  __shared__ float t[32][33];
  const int b = blockIdx.z;
  const float* ib = in + (int64_t)b * C * N;
  u16* ob = out + (int64_t)b * C * N;
  const int n0 = blockIdx.x * 32, c0 = blockIdx.y * 32;
  const int tr = threadIdx.x >> 3, tc = (threadIdx.x & 7) * 4;
  const float4 v = *(const float4*)&ib[(int64_t)(c0 + tr) * N + n0 + tc];
  t[tr][tc] = v.x; t[tr][tc + 1] = v.y; t[tr][tc + 2] = v.z; t[tr][tc + 3] = v.w;
  __syncthreads();
  U16x4 o;
  o.x = f2bf(t[tc][tr]);
  o.y = f2bf(t[tc + 1][tr]);
  o.z = f2bf(t[tc + 2][tr]);
  o.w = f2bf(t[tc + 3][tr]);
  *(U16x4*)&ob[(int64_t)(n0 + tr) * C + c0 + tc] = o;
}

// fp32 -> bf16 elementwise (vectorized x4)
__global__ void cvt_kernel(const float* __restrict__ in, u16* __restrict__ out, int n4) {
  const int i = blockIdx.x * 256 + threadIdx.x;
  if (i < n4) {
    const float4 v = ((const float4*)in)[i];
    U16x4 o;
    o.x = f2bf(v.x); o.y = f2bf(v.y); o.z = f2bf(v.z); o.w = f2bf(v.w);
    ((U16x4*)out)[i] = o;
  }
}

__global__ void bn_prep(const float* __restrict__ gamma, const float* __restrict__ beta,
                        const float* __restrict__ mean, const float* __restrict__ var,
                        const float* __restrict__ bw,
                        float* __restrict__ scale, float* __restrict__ shift) {
  const int i = threadIdx.x;
  const float inv = gamma[i] * rsqrtf(var[i] + 1e-5f);
  scale[i] = inv;
  shift[i] = (bw[i] - mean[i]) * inv + beta[i];
}

extern "C" void kernel_launch(void* const* d_in, const int* in_sizes, int n_in,
                              void* d_out, int out_size, void* d_ws, size_t ws_size,
                              hipStream_t stream) {
  const float* x     = (const float*)d_in[0];
  const float* x_h   = (const float*)d_in[1];
  const float* Wg    = (const float*)d_in[2];
  const float* bg    = (const float*)d_in[3];
  const float* Wt    = (const float*)d_in[4];
  const float* bt    = (const float*)d_in[5];
  const float* Wp    = (const float*)d_in[6];
  const float* bp    = (const float*)d_in[7];
  const float* Ww    = (const float*)d_in[8];
  const float* bw    = (const float*)d_in[9];
  const float* gamma = (const float*)d_in[10];
  const float* beta  = (const float*)d_in[11];
  const float* rmean = (const float*)d_in[12];
  const float* rvar  = (const float*)d_in[13];
  float* out = (float*)d_out;

  const int Bsz = 32, D = 512, N = 1152;
  const int64_t bsDN = (int64_t)D * N;   // 589824 elems
  const int64_t bsDD = (int64_t)D * D;   // 262144 elems

  char* ws = (char*)d_ws;
  u16* WgB = (u16*)(ws);
  u16* WtB = (u16*)(ws + 512 * 1024);
  u16* WpB = (u16*)(ws + 1024 * 1024);
  u16* WwB = (u16*)(ws + 1536 * 1024);
  float* bnscale = (float*)(ws + 2 * 1024 * 1024);
  float* bnshift = (float*)(ws + 2 * 1024 * 1024 + 4096);
  const size_t SLOT = (size_t)Bsz * bsDN * sizeof(u16);  // 37,748,736 B
  char* big = ws + 2359296;  // 2.25 MB, 256-aligned
  u16* S1 = (u16*)(big + 0 * SLOT);  // xT   -> att
  u16* S2 = (u16*)(big + 1 * SLOT);  // xhT  -> yT
  u16* S3 = (u16*)(big + 2 * SLOT);  // theta
  u16* S4 = (u16*)(big + 3 * SLOT);  // phi
  u16* S5 = (u16*)(big + 4 * SLOT);  // gT
  // total ws use: 2.25MB + 5*36MB = ~182.3 MB

  // 1) convert weights to bf16, prep BN scale/shift
  const int n4 = D * D / 4;
  cvt_kernel<<<dim3((n4 + 255) / 256), 256, 0, stream>>>(Wg, WgB, n4);
  cvt_kernel<<<dim3((n4 + 255) / 256), 256, 0, stream>>>(Wt, WtB, n4);
  cvt_kernel<<<dim3((n4 + 255) / 256), 256, 0, stream>>>(Wp, WpB, n4);
  cvt_kernel<<<dim3((n4 + 255) / 256), 256, 0, stream>>>(Ww, WwB, n4);
  bn_prep<<<1, 512, 0, stream>>>(gamma, beta, rmean, rvar, bw, bnscale, bnshift);

  // 2) transpose+convert inputs: xT, xhT : [B][1152][512] bf16
  dim3 tg(N / 32, D / 32, Bsz);
  transpose_cvt<<<tg, 256, 0, stream>>>(x, S1, D, N);
  transpose_cvt<<<tg, 256, 0, stream>>>(x_h, S2, D, N);

  // 3) theta = Wt @ x + bt  : [B][512][1152]
  gemm_abt<1><<<dim3(N / 128, D / 128, Bsz), 256, 0, stream>>>(
      WtB, 0, S1, bsDN, S3, bsDN, D, N, D, bt, nullptr, nullptr);
  // 4) phi = Wp @ x_h + bp : [B][512][1152]
  gemm_abt<1><<<dim3(N / 128, D / 128, Bsz), 256, 0, stream>>>(
      WpB, 0, S2, bsDN, S4, bsDN, D, N, D, bp, nullptr, nullptr);
  // 5) gT[n][j] = g[j][n] = (Wg @ x_h + bg)^T : [B][1152][512]
  gemm_abt<2><<<dim3(D / 128, N / 128, Bsz), 256, 0, stream>>>(
      S2, bsDN, WgB, 0, S5, bsDN, N, D, D, bg, nullptr, nullptr);
  // 6) att = (theta @ phi^T) / 512 : [B][512][512]   (into S1, xT dead)
  gemm_abt<3><<<dim3(D / 128, D / 128, Bsz), 256, 0, stream>>>(
      S3, bsDN, S4, bsDN, S1, bsDD, D, D, N, nullptr, nullptr, nullptr);
  // 7) yT[n][i] = y[i][n] = (att @ g)^T : [B][1152][512]  (into S2, xhT dead)
  gemm_abt<0><<<dim3(D / 128, N / 128, Bsz), 256, 0, stream>>>(
      S5, bsDN, S1, bsDD, S2, bsDN, N, D, D, nullptr, nullptr, nullptr);
  // 8) out = BN(Ww @ y + bw) + x : [B][512][1152] f32
  gemm_abt<4><<<dim3(N / 128, D / 128, Bsz), 256, 0, stream>>>(
      WwB, 0, S2, bsDN, out, bsDN, D, N, D, bnscale, bnshift, x);
}